// Round 2
// baseline (2620.523 us; speedup 1.0000x reference)
//
#include <hip/hip_runtime.h>
#include <hip/hip_fp16.h>

// Bidirectional GRU, b=32, t=2048, in=hid=256, PyTorch gate order r,z,n.
// Plan: gx = x@W_ih^T + b_ih precomputed as fp16 GEMM into d_ws (96MB),
// then 64 persistent WGs (batch x direction), one per CU, march 2048 steps
// with W_hh held as packed fp16 in registers and v_dot2_f32_f16 inner loop.

typedef __fp16 half2_t __attribute__((ext_vector_type(2)));

static constexpr int T_STEPS = 2048;
static constexpr int BATCH   = 32;
static constexpr int HID     = 256;
static constexpr int IN      = 256;
static constexpr int G3      = 768;   // 3*HID

__device__ __forceinline__ float fdot2(half2_t a, half2_t b, float c) {
#if __has_builtin(__builtin_amdgcn_fdot2)
    return __builtin_amdgcn_fdot2(a, b, c, false);
#else
    return c + (float)a[0] * (float)b[0] + (float)a[1] * (float)b[1];
#endif
}

// ---------------------------------------------------------------------------
// Kernel 1: gx[m][j] = sum_k x[m][k] * W_ih[j][k] + b_ih[j], stored fp16.
// m in [0,65536), j in [0,768). Per block: 64 M-rows x all 768 cols, K=256
// fully staged in LDS (fp32->fp16 on the fly). XOR swizzle on 8-half chunks
// breaks the stride-512B bank conflict for the B reads.
// ---------------------------------------------------------------------------
__global__ __launch_bounds__(256, 2) void gx_gemm(
        const float* __restrict__ x,
        const float* __restrict__ Wih,
        const float* __restrict__ bih,
        _Float16* __restrict__ gx) {
    __shared__ ushort As[64 * 256];   // 32KB
    __shared__ ushort Bs[64 * 256];   // 32KB  (64KB total -> 2 blocks/CU)

    const int tid = threadIdx.x;
    const int m0  = blockIdx.x * 64;
    const int tx  = tid & 15;         // n-dim
    const int ty  = tid >> 4;         // m-dim

    // ---- stage A tile (x): 64 rows x 256 cols ----
#pragma unroll
    for (int i = 0; i < 16; ++i) {
        int f    = tid + 256 * i;
        int row  = f >> 6;
        int col4 = f & 63;            // 4-half group index [0,64)
        float4 v = *(const float4*)(x + (size_t)(m0 + row) * IN + col4 * 4);
        half2_t h0 = __builtin_amdgcn_cvt_pkrtz(v.x, v.y);
        half2_t h1 = __builtin_amdgcn_cvt_pkrtz(v.z, v.w);
        int chunk = col4 >> 1;
        int idx = row * 256 + ((chunk ^ (row & 7)) * 8) + (col4 & 1) * 4;
        uint2 wv;
        wv.x = __builtin_bit_cast(unsigned, h0);
        wv.y = __builtin_bit_cast(unsigned, h1);
        *(uint2*)(As + idx) = wv;
    }

    for (int nb = 0; nb < 12; ++nb) {
        // ---- stage B tile (W_ih rows nb*64 .. nb*64+63) ----
#pragma unroll
        for (int i = 0; i < 16; ++i) {
            int f    = tid + 256 * i;
            int row  = f >> 6;
            int col4 = f & 63;
            float4 v = *(const float4*)(Wih + (size_t)(nb * 64 + row) * IN + col4 * 4);
            half2_t h0 = __builtin_amdgcn_cvt_pkrtz(v.x, v.y);
            half2_t h1 = __builtin_amdgcn_cvt_pkrtz(v.z, v.w);
            int chunk = col4 >> 1;
            int idx = row * 256 + ((chunk ^ (row & 7)) * 8) + (col4 & 1) * 4;
            uint2 wv;
            wv.x = __builtin_bit_cast(unsigned, h0);
            wv.y = __builtin_bit_cast(unsigned, h1);
            *(uint2*)(Bs + idx) = wv;
        }
        __syncthreads();

        float acc[4][4];
#pragma unroll
        for (int jm = 0; jm < 4; ++jm)
#pragma unroll
            for (int jn = 0; jn < 4; ++jn) acc[jm][jn] = 0.f;

#pragma unroll 4
        for (int kc = 0; kc < 32; ++kc) {
            union { uint4 u; half2_t h[4]; } av[4], bv[4];
#pragma unroll
            for (int jm = 0; jm < 4; ++jm) {
                int r = ty * 4 + jm;
                av[jm].u = *(const uint4*)(As + r * 256 + ((kc ^ (r & 7)) * 8));
            }
#pragma unroll
            for (int jn = 0; jn < 4; ++jn) {
                int r = tx + 16 * jn;
                bv[jn].u = *(const uint4*)(Bs + r * 256 + ((kc ^ (r & 7)) * 8));
            }
#pragma unroll
            for (int jm = 0; jm < 4; ++jm)
#pragma unroll
                for (int jn = 0; jn < 4; ++jn)
#pragma unroll
                    for (int p = 0; p < 4; ++p)
                        acc[jm][jn] = fdot2(av[jm].h[p], bv[jn].h[p], acc[jm][jn]);
        }

        // ---- epilogue: + bias, store fp16 ----
#pragma unroll
        for (int jn = 0; jn < 4; ++jn) {
            int n = nb * 64 + tx + 16 * jn;
            float bias = bih[n];
#pragma unroll
            for (int jm = 0; jm < 4; ++jm) {
                int m = m0 + ty * 4 + jm;
                gx[(size_t)m * G3 + n] = (_Float16)(acc[jm][jn] + bias);
            }
        }
        __syncthreads();   // protect Bs restage (WAR)
    }
}

// ---------------------------------------------------------------------------
// Kernel 2: the recurrence. grid=64 (b,dir), block=512 (8 waves).
// Wave w: k-segment s=w&3 (64 k's), row-group g=w>>2 (384 rows).
// Lane owns 6 rows x 64 k of W_hh as 192 packed fp16 VGPRs.
// Per step: broadcast-read h from LDS, 192 dot2, partials -> LDS [4][768],
// 256 lanes gate in fp32, h written back as fp16. 2 barriers/step.
// ---------------------------------------------------------------------------
__global__ __launch_bounds__(512, 2) void gru_seq(
        const _Float16* __restrict__ gx,
        const float* __restrict__ Whh,
        const float* __restrict__ bhh,
        float* __restrict__ out0,     // outputs [32,2048,512]
        float* __restrict__ out1) {   // hiddens [2048,32,512]
    __shared__ float  P[4 * 768];     // 12KB partials
    __shared__ ushort h16[256];       // h as fp16
    __shared__ ushort gxb[768];       // this step's gx row (fp16)

    const int tid = threadIdx.x;
    const int b   = blockIdx.x & 31;
    const int d   = blockIdx.x >> 5;
    const int w   = tid >> 6;
    const int L   = tid & 63;
    const int s   = w & 3;            // k segment
    const int g   = w >> 2;           // row group

    // ---- load W_hh fragment into registers as packed fp16 ----
    half2_t Wr[6][32];
#pragma unroll
    for (int jr = 0; jr < 6; ++jr) {
        const float* wrow = Whh + (size_t)(g * 384 + jr * 64 + L) * HID + s * 64;
#pragma unroll
        for (int q = 0; q < 32; ++q) {
            float2 wv = *(const float2*)(wrow + 2 * q);
            Wr[jr][q] = __builtin_amdgcn_cvt_pkrtz(wv.x, wv.y);
        }
    }

    float bh_r = 0.f, bh_z = 0.f, bh_n = 0.f, hprev = 0.f;
    if (tid < 256) {
        bh_r = bhh[tid];
        bh_z = bhh[256 + tid];
        bh_n = bhh[512 + tid];
        h16[tid] = 0;                 // h0 = 0
    }
    __syncthreads();

    const size_t gxbase = (size_t)b * T_STEPS * G3;

    for (int t = 0; t < T_STEPS; ++t) {
        const int tp = d ? (T_STEPS - 1 - t) : t;   // physical time = output index

        // prefetch this step's gx row (768 halfs) into regs; land in LDS later
        uint4 gxv;
        if (tid < 96)
            gxv = *(const uint4*)(gx + gxbase + (size_t)tp * G3 + tid * 8);

        // ---- dot phase: acc[jr] = sum_{k in seg} Whh[row][k] * h[k] ----
        float acc[6] = {0.f, 0.f, 0.f, 0.f, 0.f, 0.f};
#pragma unroll
        for (int c = 0; c < 4; ++c) {
            union { uint4 u; half2_t h[4]; } hh0, hh1;
            hh0.u = *(const uint4*)(h16 + s * 64 + c * 16);       // broadcast
            hh1.u = *(const uint4*)(h16 + s * 64 + c * 16 + 8);   // broadcast
#pragma unroll
            for (int jr = 0; jr < 6; ++jr) {
#pragma unroll
                for (int p = 0; p < 4; ++p) {
                    acc[jr] = fdot2(Wr[jr][c * 8 + p],     hh0.h[p], acc[jr]);
                    acc[jr] = fdot2(Wr[jr][c * 8 + 4 + p], hh1.h[p], acc[jr]);
                }
            }
        }
#pragma unroll
        for (int jr = 0; jr < 6; ++jr)
            P[s * 768 + g * 384 + jr * 64 + L] = acc[jr];

        if (tid < 96)
            *(uint4*)(gxb + tid * 8) = gxv;   // compiler waits vmcnt here

        __syncthreads();

        // ---- gate phase (first 4 waves) ----
        if (tid < 256) {
            const int i = tid;
            float hr = P[i]       + P[768 + i]       + P[1536 + i]       + P[2304 + i];
            float hz = P[256 + i] + P[768 + 256 + i] + P[1536 + 256 + i] + P[2304 + 256 + i];
            float hn = P[512 + i] + P[768 + 512 + i] + P[1536 + 512 + i] + P[2304 + 512 + i];
            const _Float16* gxh = (const _Float16*)gxb;
            float gr = (float)gxh[i];
            float gz = (float)gxh[256 + i];
            float gn = (float)gxh[512 + i];

            float r = 1.f / (1.f + __expf(-(gr + hr + bh_r)));
            float z = 1.f / (1.f + __expf(-(gz + hz + bh_z)));
            float nx = gn + r * (hn + bh_n);
            nx = fminf(fmaxf(nx, -15.f), 15.f);
            float e = __expf(2.f * nx);
            float n = (e - 1.f) / (e + 1.f);      // tanh(nx)
            float h = n + z * (hprev - n);
            hprev = h;

            h16[i] = __builtin_bit_cast(ushort, (_Float16)h);
            out0[((size_t)b * T_STEPS + tp) * 512 + d * 256 + i] = h;
            out1[((size_t)tp * BATCH + b) * 512 + d * 256 + i]   = h;
        }
        __syncthreads();
    }
}

// ---------------------------------------------------------------------------
extern "C" void kernel_launch(void* const* d_in, const int* in_sizes, int n_in,
                              void* d_out, int out_size, void* d_ws, size_t ws_size,
                              hipStream_t stream) {
    const float* x   = (const float*)d_in[0];
    const float* Wih = (const float*)d_in[1];
    const float* Whh = (const float*)d_in[2];
    const float* bih = (const float*)d_in[3];
    const float* bhh = (const float*)d_in[4];

    float* out0 = (float*)d_out;                          // outputs [32,2048,512]
    float* out1 = out0 + (size_t)BATCH * T_STEPS * 512;   // hiddens [2048,32,512]

    _Float16* gx = (_Float16*)d_ws;                       // 65536*768*2 = 96MB

    gx_gemm<<<dim3(65536 / 64), dim3(256), 0, stream>>>(x, Wih, bih, gx);
    gru_seq<<<dim3(BATCH * 2), dim3(512), 0, stream>>>(gx, Whh, bhh, out0, out1);
}

// Round 3
// 2565.018 us; speedup vs baseline: 1.0216x; 1.0216x over previous
//
#include <hip/hip_runtime.h>
#include <hip/hip_fp16.h>

// Bidirectional GRU, b=32, t=2048, in=hid=256, gate order r,z,n.
// gx = x@W_ih^T + b_ih precomputed fp16 in d_ws; recurrence on 64 WGs
// (batch x dir), 768 threads = 12 waves = 4 k-segments x 3 row-groups.
// Per lane: 4 rows x 64 k of W_hh as 128 packed-fp16 VGPRs (fits arch
// VGPR budget at 3 waves/SIMD -> no AGPR copy tax, unlike the 512-thread
// version). Barriers are lgkmcnt-only so output-store acks and the gx
// prefetch stay in flight across them.

typedef __fp16 half2_t __attribute__((ext_vector_type(2)));

static constexpr int T_STEPS = 2048;
static constexpr int BATCH   = 32;
static constexpr int HID     = 256;
static constexpr int IN      = 256;
static constexpr int G3      = 768;   // 3*HID

__device__ __forceinline__ float fdot2(half2_t a, half2_t b, float c) {
    return __builtin_amdgcn_fdot2(a, b, c, false);
}

// __syncthreads() drains vmcnt(0) (store acks + prefetch) -- we only need
// LDS ordering, so wait lgkmcnt(0) and barrier.
__device__ __forceinline__ void barrier_lgkm() {
    asm volatile("s_waitcnt lgkmcnt(0)\n\ts_barrier" ::: "memory");
}

// ---------------------------------------------------------------------------
// Kernel 1: gx[m][j] = sum_k x[m][k] * W_ih[j][k] + b_ih[j], stored fp16.
// ---------------------------------------------------------------------------
__global__ __launch_bounds__(256, 2) void gx_gemm(
        const float* __restrict__ x,
        const float* __restrict__ Wih,
        const float* __restrict__ bih,
        _Float16* __restrict__ gx) {
    __shared__ ushort As[64 * 256];   // 32KB
    __shared__ ushort Bs[64 * 256];   // 32KB

    const int tid = threadIdx.x;
    const int m0  = blockIdx.x * 64;
    const int tx  = tid & 15;         // n-dim
    const int ty  = tid >> 4;         // m-dim

    // ---- stage A tile (x): 64 rows x 256 cols ----
#pragma unroll
    for (int i = 0; i < 16; ++i) {
        int f    = tid + 256 * i;
        int row  = f >> 6;
        int col4 = f & 63;
        float4 v = *(const float4*)(x + (size_t)(m0 + row) * IN + col4 * 4);
        half2_t h0 = __builtin_amdgcn_cvt_pkrtz(v.x, v.y);
        half2_t h1 = __builtin_amdgcn_cvt_pkrtz(v.z, v.w);
        int chunk = col4 >> 1;
        int idx = row * 256 + ((chunk ^ (row & 7)) * 8) + (col4 & 1) * 4;
        uint2 wv;
        wv.x = __builtin_bit_cast(unsigned, h0);
        wv.y = __builtin_bit_cast(unsigned, h1);
        *(uint2*)(As + idx) = wv;
    }

    for (int nb = 0; nb < 12; ++nb) {
#pragma unroll
        for (int i = 0; i < 16; ++i) {
            int f    = tid + 256 * i;
            int row  = f >> 6;
            int col4 = f & 63;
            float4 v = *(const float4*)(Wih + (size_t)(nb * 64 + row) * IN + col4 * 4);
            half2_t h0 = __builtin_amdgcn_cvt_pkrtz(v.x, v.y);
            half2_t h1 = __builtin_amdgcn_cvt_pkrtz(v.z, v.w);
        int chunk = col4 >> 1;
            int idx = row * 256 + ((chunk ^ (row & 7)) * 8) + (col4 & 1) * 4;
            uint2 wv;
            wv.x = __builtin_bit_cast(unsigned, h0);
            wv.y = __builtin_bit_cast(unsigned, h1);
            *(uint2*)(Bs + idx) = wv;
        }
        barrier_lgkm();

        float acc[4][4];
#pragma unroll
        for (int jm = 0; jm < 4; ++jm)
#pragma unroll
            for (int jn = 0; jn < 4; ++jn) acc[jm][jn] = 0.f;

#pragma unroll 4
        for (int kc = 0; kc < 32; ++kc) {
            union { uint4 u; half2_t h[4]; } av[4], bv[4];
#pragma unroll
            for (int jm = 0; jm < 4; ++jm) {
                int r = ty * 4 + jm;
                av[jm].u = *(const uint4*)(As + r * 256 + ((kc ^ (r & 7)) * 8));
            }
#pragma unroll
            for (int jn = 0; jn < 4; ++jn) {
                int r = tx + 16 * jn;
                bv[jn].u = *(const uint4*)(Bs + r * 256 + ((kc ^ (r & 7)) * 8));
            }
#pragma unroll
            for (int jm = 0; jm < 4; ++jm)
#pragma unroll
                for (int jn = 0; jn < 4; ++jn)
#pragma unroll
                    for (int p = 0; p < 4; ++p)
                        acc[jm][jn] = fdot2(av[jm].h[p], bv[jn].h[p], acc[jm][jn]);
        }

#pragma unroll
        for (int jn = 0; jn < 4; ++jn) {
            int n = nb * 64 + tx + 16 * jn;
            float bias = bih[n];
#pragma unroll
            for (int jm = 0; jm < 4; ++jm) {
                int m = m0 + ty * 4 + jm;
                gx[(size_t)m * G3 + n] = (_Float16)(acc[jm][jn] + bias);
            }
        }
        barrier_lgkm();   // WAR: Bs restage next iteration
    }
}

// ---------------------------------------------------------------------------
// Kernel 2: recurrence. grid=64 (b,dir), block=768 (12 waves).
// Wave w: k-segment s=w&3 (64 k), row-group g=w>>2 (256 rows).
// Lane: 4 rows x 64 k of W_hh = 128 packed fp16 VGPRs. b_hh folded into
// acc init on s==0 waves. 2 lgkm-only barriers/step.
// ---------------------------------------------------------------------------
__global__ __launch_bounds__(768, 3) void gru_seq(
        const _Float16* __restrict__ gx,
        const float* __restrict__ Whh,
        const float* __restrict__ bhh,
        float* __restrict__ out0,     // outputs [32,2048,512]
        float* __restrict__ out1) {   // hiddens [2048,32,512]
    __shared__ float  P[4 * 768];     // 12KB partials
    __shared__ ushort h16[256];       // h as fp16
    __shared__ ushort gxb[768];       // this step's gx row (fp16)

    const int tid = threadIdx.x;
    const int b   = blockIdx.x & 31;
    const int d   = blockIdx.x >> 5;
    const int w   = tid >> 6;
    const int L   = tid & 63;
    const int s   = w & 3;            // k segment
    const int g   = w >> 2;           // row group (0..2)

    // ---- W_hh fragment -> registers as packed fp16; bias on s==0 ----
    half2_t Wr[4][32];
    float   Wb[4];
#pragma unroll
    for (int jr = 0; jr < 4; ++jr) {
        const int row = g * 256 + jr * 64 + L;
        const float* wrow = Whh + (size_t)row * HID + s * 64;
#pragma unroll
        for (int q = 0; q < 32; ++q) {
            float2 wv = *(const float2*)(wrow + 2 * q);
            Wr[jr][q] = __builtin_amdgcn_cvt_pkrtz(wv.x, wv.y);
        }
        Wb[jr] = (s == 0) ? bhh[row] : 0.f;
    }

    float hprev = 0.f;
    if (tid < 256) h16[tid] = 0;      // h0 = 0

    const int tp0 = d ? (T_STEPS - 1) : 0;
    const int sgn = d ? -1 : 1;

    const _Float16* gp = gx + ((size_t)b * T_STEPS + tp0) * G3 + tid * 8;
    const int gpd = sgn * G3;
    uint4 greg{};
    if (tid < 96) greg = *(const uint4*)gp;

    float* o0 = out0 + ((size_t)b * T_STEPS + tp0) * 512 + d * 256 + tid;
    float* o1 = out1 + ((size_t)tp0 * BATCH + b) * 512 + d * 256 + tid;
    const int o0d = sgn * 512;
    const int o1d = sgn * (BATCH * 512);

    __syncthreads();

    for (int t = 0; t < T_STEPS; ++t) {
        // land this step's gx row in LDS; issue next step's load (hides HBM
        // latency under dot+gate; lgkm-only barriers keep it in flight)
        if (tid < 96) {
            *(uint4*)(gxb + tid * 8) = greg;
            if (t + 1 < T_STEPS) {
                gp += gpd;
                greg = *(const uint4*)gp;
            }
        }

        // ---- dot phase: 128 fdot2 per lane ----
        float acc[4] = {Wb[0], Wb[1], Wb[2], Wb[3]};
#pragma unroll
        for (int c = 0; c < 4; ++c) {
            union { uint4 u; half2_t h[4]; } hh0, hh1;
            hh0.u = *(const uint4*)(h16 + s * 64 + c * 16);       // broadcast
            hh1.u = *(const uint4*)(h16 + s * 64 + c * 16 + 8);   // broadcast
#pragma unroll
            for (int jr = 0; jr < 4; ++jr) {
#pragma unroll
                for (int p = 0; p < 4; ++p) {
                    acc[jr] = fdot2(Wr[jr][c * 8 + p],     hh0.h[p], acc[jr]);
                    acc[jr] = fdot2(Wr[jr][c * 8 + 4 + p], hh1.h[p], acc[jr]);
                }
            }
        }
#pragma unroll
        for (int jr = 0; jr < 4; ++jr)
            P[s * 768 + g * 256 + jr * 64 + L] = acc[jr];

        barrier_lgkm();

        // ---- gate phase (first 4 waves) ----
        if (tid < 256) {
            const int i = tid;
            float hr = (P[i]       + P[768 + i])  + (P[1536 + i] + P[2304 + i]);
            float hz = (P[256 + i] + P[1024 + i]) + (P[1792 + i] + P[2560 + i]);
            float hn = (P[512 + i] + P[1280 + i]) + (P[2048 + i] + P[2816 + i]);
            const _Float16* gxh = (const _Float16*)gxb;
            float xr = (float)gxh[i]       + hr;
            float xz = (float)gxh[256 + i] + hz;
            // sigmoid via exp2; saturates cleanly at +-inf (no NaN)
            float r = __builtin_amdgcn_rcpf(1.f + __builtin_amdgcn_exp2f(xr * -1.44269504f));
            float z = __builtin_amdgcn_rcpf(1.f + __builtin_amdgcn_exp2f(xz * -1.44269504f));
            float nx = (float)gxh[512 + i] + r * hn;   // hn includes b_hn
            float e2 = __builtin_amdgcn_exp2f(nx * 2.88539008f);
            float n  = 1.f - 2.f * __builtin_amdgcn_rcpf(1.f + e2);   // tanh
            float h  = n + z * (hprev - n);
            hprev = h;

            h16[i] = __builtin_bit_cast(ushort, (_Float16)h);
            *o0 = h; *o1 = h;
            o0 += o0d; o1 += o1d;
        }
        barrier_lgkm();
    }
}

// ---------------------------------------------------------------------------
extern "C" void kernel_launch(void* const* d_in, const int* in_sizes, int n_in,
                              void* d_out, int out_size, void* d_ws, size_t ws_size,
                              hipStream_t stream) {
    const float* x   = (const float*)d_in[0];
    const float* Wih = (const float*)d_in[1];
    const float* Whh = (const float*)d_in[2];
    const float* bih = (const float*)d_in[3];
    const float* bhh = (const float*)d_in[4];

    float* out0 = (float*)d_out;                          // outputs [32,2048,512]
    float* out1 = out0 + (size_t)BATCH * T_STEPS * 512;   // hiddens [2048,32,512]

    _Float16* gx = (_Float16*)d_ws;                       // 96MB

    gx_gemm<<<dim3(65536 / 64), dim3(256), 0, stream>>>(x, Wih, bih, gx);
    gru_seq<<<dim3(BATCH * 2), dim3(768), 0, stream>>>(gx, Whh, bhh, out0, out1);
}

// Round 4
// 2553.210 us; speedup vs baseline: 1.0264x; 1.0046x over previous
//
#include <hip/hip_runtime.h>
#include <hip/hip_fp16.h>

// Bidirectional GRU, b=32, t=2048, in=hid=256, gate order r,z,n.
// gx = x@W_ih^T + b_ih precomputed fp16 in d_ws; recurrence on 64 WGs
// (batch x dir), 768 threads = 12 waves = 4 k-segments x 3 row-groups.
// Per lane: 4 rows x 64 k of W_hh as 128 packed-fp16 VGPRs.
// R4 change: amdgpu_waves_per_eu(3,3) pins the allocator's occupancy
// target so Wr stays in ARCH VGPRs (R3's VGPR_Count=84 proved it was
// being parked in AGPRs, costing ~900 extra VALU cyc/step on copies).

typedef __fp16 half2_t __attribute__((ext_vector_type(2)));

static constexpr int T_STEPS = 2048;
static constexpr int BATCH   = 32;
static constexpr int HID     = 256;
static constexpr int IN      = 256;
static constexpr int G3      = 768;   // 3*HID

__device__ __forceinline__ float fdot2(half2_t a, half2_t b, float c) {
    return __builtin_amdgcn_fdot2(a, b, c, false);
}

// __syncthreads() drains vmcnt(0) (store acks + prefetch) -- we only need
// LDS ordering, so wait lgkmcnt(0) and barrier.
__device__ __forceinline__ void barrier_lgkm() {
    asm volatile("s_waitcnt lgkmcnt(0)\n\ts_barrier" ::: "memory");
}

// ---------------------------------------------------------------------------
// Kernel 1: gx[m][j] = sum_k x[m][k] * W_ih[j][k] + b_ih[j], stored fp16.
// ---------------------------------------------------------------------------
__global__ __launch_bounds__(256, 2) void gx_gemm(
        const float* __restrict__ x,
        const float* __restrict__ Wih,
        const float* __restrict__ bih,
        _Float16* __restrict__ gx) {
    __shared__ ushort As[64 * 256];   // 32KB
    __shared__ ushort Bs[64 * 256];   // 32KB

    const int tid = threadIdx.x;
    const int m0  = blockIdx.x * 64;
    const int tx  = tid & 15;         // n-dim
    const int ty  = tid >> 4;         // m-dim

    // ---- stage A tile (x): 64 rows x 256 cols ----
#pragma unroll
    for (int i = 0; i < 16; ++i) {
        int f    = tid + 256 * i;
        int row  = f >> 6;
        int col4 = f & 63;
        float4 v = *(const float4*)(x + (size_t)(m0 + row) * IN + col4 * 4);
        half2_t h0 = __builtin_amdgcn_cvt_pkrtz(v.x, v.y);
        half2_t h1 = __builtin_amdgcn_cvt_pkrtz(v.z, v.w);
        int chunk = col4 >> 1;
        int idx = row * 256 + ((chunk ^ (row & 7)) * 8) + (col4 & 1) * 4;
        uint2 wv;
        wv.x = __builtin_bit_cast(unsigned, h0);
        wv.y = __builtin_bit_cast(unsigned, h1);
        *(uint2*)(As + idx) = wv;
    }

    for (int nb = 0; nb < 12; ++nb) {
#pragma unroll
        for (int i = 0; i < 16; ++i) {
            int f    = tid + 256 * i;
            int row  = f >> 6;
            int col4 = f & 63;
            float4 v = *(const float4*)(Wih + (size_t)(nb * 64 + row) * IN + col4 * 4);
            half2_t h0 = __builtin_amdgcn_cvt_pkrtz(v.x, v.y);
            half2_t h1 = __builtin_amdgcn_cvt_pkrtz(v.z, v.w);
            int chunk = col4 >> 1;
            int idx = row * 256 + ((chunk ^ (row & 7)) * 8) + (col4 & 1) * 4;
            uint2 wv;
            wv.x = __builtin_bit_cast(unsigned, h0);
            wv.y = __builtin_bit_cast(unsigned, h1);
            *(uint2*)(Bs + idx) = wv;
        }
        barrier_lgkm();

        float acc[4][4];
#pragma unroll
        for (int jm = 0; jm < 4; ++jm)
#pragma unroll
            for (int jn = 0; jn < 4; ++jn) acc[jm][jn] = 0.f;

#pragma unroll 4
        for (int kc = 0; kc < 32; ++kc) {
            union { uint4 u; half2_t h[4]; } av[4], bv[4];
#pragma unroll
            for (int jm = 0; jm < 4; ++jm) {
                int r = ty * 4 + jm;
                av[jm].u = *(const uint4*)(As + r * 256 + ((kc ^ (r & 7)) * 8));
            }
#pragma unroll
            for (int jn = 0; jn < 4; ++jn) {
                int r = tx + 16 * jn;
                bv[jn].u = *(const uint4*)(Bs + r * 256 + ((kc ^ (r & 7)) * 8));
            }
#pragma unroll
            for (int jm = 0; jm < 4; ++jm)
#pragma unroll
                for (int jn = 0; jn < 4; ++jn)
#pragma unroll
                    for (int p = 0; p < 4; ++p)
                        acc[jm][jn] = fdot2(av[jm].h[p], bv[jn].h[p], acc[jm][jn]);
        }

#pragma unroll
        for (int jn = 0; jn < 4; ++jn) {
            int n = nb * 64 + tx + 16 * jn;
            float bias = bih[n];
#pragma unroll
            for (int jm = 0; jm < 4; ++jm) {
                int m = m0 + ty * 4 + jm;
                gx[(size_t)m * G3 + n] = (_Float16)(acc[jm][jn] + bias);
            }
        }
        barrier_lgkm();   // WAR: Bs restage next iteration
    }
}

// ---------------------------------------------------------------------------
// Kernel 2: recurrence. grid=64 (b,dir), block=768 (12 waves).
// Wave w: k-segment s=w&3 (64 k), row-group g=w>>2 (256 rows).
// Lane: 4 rows x 64 k of W_hh = 128 packed fp16 VGPRs. b_hh folded into
// acc init on s==0 waves. 2 lgkm-only barriers/step.
// waves_per_eu(3,3): pin occupancy target == actual (12 waves/CU) so the
// allocator keeps the 128-reg weight array in arch VGPRs, not AGPRs.
// ---------------------------------------------------------------------------
__attribute__((amdgpu_waves_per_eu(3, 3)))
__global__ __launch_bounds__(768) void gru_seq(
        const _Float16* __restrict__ gx,
        const float* __restrict__ Whh,
        const float* __restrict__ bhh,
        float* __restrict__ out0,     // outputs [32,2048,512]
        float* __restrict__ out1) {   // hiddens [2048,32,512]
    __shared__ float  P[4 * 768];     // 12KB partials
    __shared__ ushort h16[256];       // h as fp16
    __shared__ ushort gxb[768];       // this step's gx row (fp16)

    const int tid = threadIdx.x;
    const int b   = blockIdx.x & 31;
    const int d   = blockIdx.x >> 5;
    const int w   = tid >> 6;
    const int L   = tid & 63;
    const int s   = w & 3;            // k segment
    const int g   = w >> 2;           // row group (0..2)

    // ---- W_hh fragment -> registers as packed fp16; bias on s==0 ----
    half2_t Wr[4][32];
    float   Wb[4];
#pragma unroll
    for (int jr = 0; jr < 4; ++jr) {
        const int row = g * 256 + jr * 64 + L;
        const float* wrow = Whh + (size_t)row * HID + s * 64;
#pragma unroll
        for (int q = 0; q < 32; ++q) {
            float2 wv = *(const float2*)(wrow + 2 * q);
            Wr[jr][q] = __builtin_amdgcn_cvt_pkrtz(wv.x, wv.y);
        }
        Wb[jr] = (s == 0) ? bhh[row] : 0.f;
    }

    float hprev = 0.f;
    if (tid < 256) h16[tid] = 0;      // h0 = 0

    const int tp0 = d ? (T_STEPS - 1) : 0;
    const int sgn = d ? -1 : 1;

    const _Float16* gp = gx + ((size_t)b * T_STEPS + tp0) * G3 + tid * 8;
    const int gpd = sgn * G3;
    uint4 greg{};
    if (tid < 96) greg = *(const uint4*)gp;

    float* o0 = out0 + ((size_t)b * T_STEPS + tp0) * 512 + d * 256 + tid;
    float* o1 = out1 + ((size_t)tp0 * BATCH + b) * 512 + d * 256 + tid;
    const int o0d = sgn * 512;
    const int o1d = sgn * (BATCH * 512);

    __syncthreads();

    for (int t = 0; t < T_STEPS; ++t) {
        // land this step's gx row in LDS; issue next step's load (hides HBM
        // latency under dot+gate; lgkm-only barriers keep it in flight)
        if (tid < 96) {
            *(uint4*)(gxb + tid * 8) = greg;
            if (t + 1 < T_STEPS) {
                gp += gpd;
                greg = *(const uint4*)gp;
            }
        }

        // ---- dot phase: 128 fdot2 per lane ----
        float acc[4] = {Wb[0], Wb[1], Wb[2], Wb[3]};
#pragma unroll
        for (int c = 0; c < 4; ++c) {
            union { uint4 u; half2_t h[4]; } hh0, hh1;
            hh0.u = *(const uint4*)(h16 + s * 64 + c * 16);       // broadcast
            hh1.u = *(const uint4*)(h16 + s * 64 + c * 16 + 8);   // broadcast
#pragma unroll
            for (int jr = 0; jr < 4; ++jr) {
#pragma unroll
                for (int p = 0; p < 4; ++p) {
                    acc[jr] = fdot2(Wr[jr][c * 8 + p],     hh0.h[p], acc[jr]);
                    acc[jr] = fdot2(Wr[jr][c * 8 + 4 + p], hh1.h[p], acc[jr]);
                }
            }
        }
#pragma unroll
        for (int jr = 0; jr < 4; ++jr)
            P[s * 768 + g * 256 + jr * 64 + L] = acc[jr];

        barrier_lgkm();

        // ---- gate phase (first 4 waves) ----
        if (tid < 256) {
            const int i = tid;
            float hr = (P[i]       + P[768 + i])  + (P[1536 + i] + P[2304 + i]);
            float hz = (P[256 + i] + P[1024 + i]) + (P[1792 + i] + P[2560 + i]);
            float hn = (P[512 + i] + P[1280 + i]) + (P[2048 + i] + P[2816 + i]);
            const _Float16* gxh = (const _Float16*)gxb;
            float xr = (float)gxh[i]       + hr;
            float xz = (float)gxh[256 + i] + hz;
            // sigmoid via exp2; saturates cleanly at +-inf (no NaN)
            float r = __builtin_amdgcn_rcpf(1.f + __builtin_amdgcn_exp2f(xr * -1.44269504f));
            float z = __builtin_amdgcn_rcpf(1.f + __builtin_amdgcn_exp2f(xz * -1.44269504f));
            float nx = (float)gxh[512 + i] + r * hn;   // hn includes b_hn
            float e2 = __builtin_amdgcn_exp2f(nx * 2.88539008f);
            float n  = 1.f - 2.f * __builtin_amdgcn_rcpf(1.f + e2);   // tanh
            float h  = n + z * (hprev - n);
            hprev = h;

            h16[i] = __builtin_bit_cast(ushort, (_Float16)h);
            *o0 = h; *o1 = h;
            o0 += o0d; o1 += o1d;
        }
        barrier_lgkm();
    }
}

// ---------------------------------------------------------------------------
extern "C" void kernel_launch(void* const* d_in, const int* in_sizes, int n_in,
                              void* d_out, int out_size, void* d_ws, size_t ws_size,
                              hipStream_t stream) {
    const float* x   = (const float*)d_in[0];
    const float* Wih = (const float*)d_in[1];
    const float* Whh = (const float*)d_in[2];
    const float* bih = (const float*)d_in[3];
    const float* bhh = (const float*)d_in[4];

    float* out0 = (float*)d_out;                          // outputs [32,2048,512]
    float* out1 = out0 + (size_t)BATCH * T_STEPS * 512;   // hiddens [2048,32,512]

    _Float16* gx = (_Float16*)d_ws;                       // 96MB

    gx_gemm<<<dim3(65536 / 64), dim3(256), 0, stream>>>(x, Wih, bih, gx);
    gru_seq<<<dim3(BATCH * 2), dim3(768), 0, stream>>>(gx, Whh, bhh, out0, out1);
}